// Round 19
// baseline (285.530 us; speedup 1.0000x reference)
//
#include <hip/hip_runtime.h>
#include <hip/hip_bf16.h>
#include <stdint.h>

typedef __bf16 bf16_t;
typedef __bf16 bf16x8 __attribute__((ext_vector_type(8)));
typedef float  f32x4  __attribute__((ext_vector_type(4)));

#define DIM    1024
#define NTOK   4096
#define NB     8
#define ROWS   (NB*NTOK)   // 32768
#define QKVC   384
#define INNER  128

// global -> LDS direct copy, 16B per lane (dest = wave-uniform base + lane*16)
#define GLD16(g, l) __builtin_amdgcn_global_load_lds( \
    (const __attribute__((address_space(1))) void*)(g), \
    (__attribute__((address_space(3))) void*)(l), 16, 0, 0)

#define VMCNT(n) asm volatile("s_waitcnt vmcnt(" #n ")" ::: "memory")
#define SBAR0()  __builtin_amdgcn_sched_barrier(0)

// workspace offsets (bytes)
#define OFF_WQ    131072u      // 384*1024 bf16   (768 KB)
#define OFF_QKV   1048576u     // 32768*384 bf16  (24 MB; only v cols written)
#define OFF_STATS 26214400u    // 256 chunks * 8 heads * 288 f32
#define OFF_ATTN  30932992u    // 8*8*16*16 f32
#define OFF_WEFF  30998528u    // 8*1024*128 bf16

// ---------- kernel 0: w_qkv * norm_weight -> bf16 ----------
__global__ __launch_bounds__(256) void k_wconv(const float* __restrict__ wq,
    const float* __restrict__ nw, bf16_t* __restrict__ wqb)
{
    int o = blockIdx.x;            // 384 rows
    int c = threadIdx.x * 4;
    float4 wv = *reinterpret_cast<const float4*>(wq + (size_t)o*DIM + c);
    float4 nv = *reinterpret_cast<const float4*>(nw + c);
    bf16_t* dst = wqb + (size_t)o*DIM + c;
    dst[0]=(bf16_t)(wv.x*nv.x); dst[1]=(bf16_t)(wv.y*nv.y);
    dst[2]=(bf16_t)(wv.z*nv.z); dst[3]=(bf16_t)(wv.w*nv.w);
}

// ---------- kernel 1: FUSED RMSNorm + QKV GEMM + Gram stats ----------
// R18 falsified "per-load latency" (2-step window: null). The real curve is
// blocks/CU (m102: same structure, 1 blk/CU=320 TF, 4 blk/CU=833 TF). R16's
// 96KB Bl dbuf forced 1 blk/CU. Here B is SINGLE-buffered (B is L2-resident;
// ~250cy latency needs no cross-step window) -> LDS 64.5 KB -> 2 blocks/CU,
// 16 waves/CU, cross-block barrier-window overlap. A keeps reg-prefetch.
// Step ledger: bar | STAGEB(kt) 6 GLD16 | WRITEA(kt) (auto-vmcnt drains A
// pair only) | LOADA(kt+1) +2 | VMCNT(2) drains the 6 GLD16, A stays |
// lgkmcnt(0) | bar | COMPUTE. SBAR0 fences pin issue order (ledger exact).
__global__ __launch_bounds__(512, 4) void k_qkv_gemm(const float* __restrict__ x,
    const bf16_t* __restrict__ wqb, bf16_t* __restrict__ qkv,
    float* __restrict__ stats)
{
    __shared__ bf16_t lds[32768];      // 64 KB: Al=[0,8192), Bl=[8192,32768)
    __shared__ float srow[128];
    bf16_t* Al = lds;
    bf16_t* Bl = lds + 8192;
    int mt = blockIdx.x;               // 256 blocks; chunk = 128 tokens
    int row0 = mt*128;
    int t = threadIdx.x;
    int lane = t & 63, lr = lane & 15, lg = lane >> 4;
    int w = t >> 6, wm = w >> 2, wn = w & 3;   // 2M x 4N wave grid

    // ---- A staging (regs): thread t owns row rA, fp32 elems fo..fo+15 of 64
    int rA = t >> 2;                   // 0..127
    int fo = (t & 3) * 16;
    const float* xrow = x + (size_t)(row0 + rA)*DIM + fo;
    int ws0 = ((t & 3)*2)     ^ (rA & 7);
    int ws1 = ((t & 3)*2 + 1) ^ (rA & 7);

    // ---- B staging (global_load_lds)
    int srB = t >> 3;                  // 0..63
    int sk8 = ((t & 7) ^ (srB & 7)) * 8;
    const bf16_t* bbase = wqb + (size_t)srB*DIM + sk8;
    int ldsoff = (t & ~63) * 8;        // wave-uniform dest base (elems)

    int rsw = lr & 7;                  // read-side slot XOR

    float4 u0, u1, u2, u3;             // 16 fp32 A staging regs

#define LOADA(kt) do {                                                   \
        const float4* _xs = reinterpret_cast<const float4*>(xrow + (kt)*64); \
        u0 = _xs[0]; u1 = _xs[1]; u2 = _xs[2]; u3 = _xs[3];              \
    } while (0)

#define STAGEB(kt) do {                                                  \
        int _ko = (kt)*64;                                               \
        _Pragma("unroll")                                                \
        for (int _c = 0; _c < 6; _c++)                                   \
            GLD16(bbase + _ko + (size_t)(64*_c)*DIM,                     \
                  &Bl[ldsoff + _c*4096]);                                \
    } while (0)

#define WRITEA() do {                                                   \
        ssq += u0.x*u0.x + u0.y*u0.y + u0.z*u0.z + u0.w*u0.w             \
             + u1.x*u1.x + u1.y*u1.y + u1.z*u1.z + u1.w*u1.w             \
             + u2.x*u2.x + u2.y*u2.y + u2.z*u2.z + u2.w*u2.w             \
             + u3.x*u3.x + u3.y*u3.y + u3.z*u3.z + u3.w*u3.w;            \
        bf16x8 _v0, _v1;                                                 \
        _v0[0]=(bf16_t)u0.x; _v0[1]=(bf16_t)u0.y; _v0[2]=(bf16_t)u0.z;   \
        _v0[3]=(bf16_t)u0.w; _v0[4]=(bf16_t)u1.x; _v0[5]=(bf16_t)u1.y;   \
        _v0[6]=(bf16_t)u1.z; _v0[7]=(bf16_t)u1.w;                        \
        _v1[0]=(bf16_t)u2.x; _v1[1]=(bf16_t)u2.y; _v1[2]=(bf16_t)u2.z;   \
        _v1[3]=(bf16_t)u2.w; _v1[4]=(bf16_t)u3.x; _v1[5]=(bf16_t)u3.y;   \
        _v1[6]=(bf16_t)u3.z; _v1[7]=(bf16_t)u3.w;                        \
        *reinterpret_cast<bf16x8*>(&Al[rA*64 + ws0*8]) = _v0;            \
        *reinterpret_cast<bf16x8*>(&Al[rA*64 + ws1*8]) = _v1;            \
    } while (0)

#define COMPUTE() do {                                                  \
        _Pragma("unroll")                                                \
        for (int kk = 0; kk < 2; kk++) {                                 \
            int kb = ((kk*4 + lg) ^ rsw) * 8;                            \
            bf16x8 af[4], bfr[6];                                        \
            _Pragma("unroll")                                            \
            for (int mi = 0; mi < 4; mi++)                               \
                af[mi] = *reinterpret_cast<const bf16x8*>(               \
                    &Al[(wm*64 + mi*16 + lr)*64 + kb]);                  \
            _Pragma("unroll")                                            \
            for (int ni = 0; ni < 6; ni++)                               \
                bfr[ni] = *reinterpret_cast<const bf16x8*>(              \
                    &Bl[(wn*96 + ni*16 + lr)*64 + kb]);                  \
            _Pragma("unroll")                                            \
            for (int mi = 0; mi < 4; mi++)                               \
                _Pragma("unroll")                                        \
                for (int ni = 0; ni < 6; ni++)                           \
                    acc[mi][ni] = __builtin_amdgcn_mfma_f32_16x16x32_bf16( \
                        af[mi], bfr[ni], acc[mi][ni], 0, 0, 0);          \
        }                                                                \
    } while (0)

    float ssq = 0.f;
    f32x4 acc[4][6] = {};

    LOADA(0);                          // prologue: A(0) in flight

    for (int kt = 0; kt < 16; kt++) {
        __builtin_amdgcn_s_barrier();  // prev COMPUTE reads done -> overwrite OK
        STAGEB(kt);                    // 6 GLD16 -> Bl
        SBAR0();
        WRITEA();                      // auto-vmcnt drains A(kt) pair (oldest)
        SBAR0();
        if (kt < 15) LOADA(kt + 1);    // +2 loads, youngest
        SBAR0();
        if (kt < 15) VMCNT(2); else VMCNT(0);   // drain 6 GLD16; A stays
        asm volatile("s_waitcnt lgkmcnt(0)" ::: "memory");
        __builtin_amdgcn_s_barrier();  // tile kt visible to all waves
        COMPUTE();
    }
#undef LOADA
#undef STAGEB
#undef WRITEA
#undef COMPUTE

    // per-row sumsq: 4 consecutive threads share row rA
    ssq += __shfl_xor(ssq, 1, 64);
    ssq += __shfl_xor(ssq, 2, 64);
    if ((t & 3) == 0) srow[rA] = rsqrtf(ssq*(1.0f/DIM) + 1e-6f);
    __syncthreads();                    // all COMPUTE(15) reads done -> lds reusable

    // epilogue: v cols (>=256) -> global; q,k cols (<256) -> LDS qk tile
    bf16_t* qk = lds;                   // 128 x 256 row-major = 64 KB (Al∪Bl)
    #pragma unroll
    for (int mi = 0; mi < 4; mi++)
        #pragma unroll
        for (int ni = 0; ni < 6; ni++) {
            int col_g = wn*96 + ni*16 + lr;
            #pragma unroll
            for (int rr = 0; rr < 4; rr++) {
                int rloc = wm*64 + mi*16 + lg*4 + rr;
                bf16_t val = (bf16_t)(acc[mi][ni][rr] * srow[rloc]);
                if (wn*96 + ni*16 >= 256)       // (wn,ni)-uniform branch
                    qkv[(size_t)(row0 + rloc)*QKVC + col_g] = val;
                else
                    qk[rloc*256 + col_g] = val;
            }
        }
    __syncthreads();

    // Gram phase: wave w = head h; gram[i][j] = sum_t q[t][h16+i]*k[t][h16+j]
    {
        int h = w;
        f32x4 g = {};
        #pragma unroll
        for (int ks = 0; ks < 4; ks++) {
            bf16x8 afr, bfr2;
            #pragma unroll
            for (int e = 0; e < 8; e++) {
                int tt = ks*32 + lg*8 + e;
                afr[e]  = qk[tt*256 + h*16 + lr];
                bfr2[e] = qk[tt*256 + 128 + h*16 + lr];
            }
            g = __builtin_amdgcn_mfma_f32_16x16x32_bf16(afr, bfr2, g, 0, 0, 0);
        }
        float* base = stats + ((size_t)mt*8 + h)*288;
        #pragma unroll
        for (int reg = 0; reg < 4; reg++)
            base[(lg*4 + reg)*16 + lr] = g[reg];   // row=lg*4+reg, col=lr
        float qs = 0.f, ks2 = 0.f;
        #pragma unroll
        for (int e = 0; e < 32; e++) {
            int tt = lg*32 + e;
            float qv = (float)qk[tt*256 + h*16 + lr];
            float kv = (float)qk[tt*256 + 128 + h*16 + lr];
            qs += qv*qv; ks2 += kv*kv;
        }
        qs  += __shfl_xor(qs, 16, 64);  qs  += __shfl_xor(qs, 32, 64);
        ks2 += __shfl_xor(ks2, 16, 64); ks2 += __shfl_xor(ks2, 32, 64);
        if (lane < 16) { base[256 + lr] = qs; base[272 + lr] = ks2; }
    }
}

// ---------- kernel 2: reduce partials, l2-normalize, temperature, softmax ----------
__global__ __launch_bounds__(256) void k_attn(const float* __restrict__ stats,
    const float* __restrict__ temp, float* __restrict__ attn)
{
    int bid = blockIdx.x;           // 64 = 8b * 8h
    int b = bid >> 3, h = bid & 7;
    int t = threadIdx.x, i = t >> 4, j = t & 15;
    float gsum = 0.f, qs = 0.f, ks = 0.f;
    for (int ch = 0; ch < 32; ch++) {        // 32 chunks of 128 tokens
        const float* base = stats + ((size_t)(b*32 + ch)*8 + h)*288;
        gsum += base[i*16 + j];
        qs   += base[256 + i];
        ks   += base[272 + j];
    }
    float et  = expf(temp[h]);
    float sim = gsum * et / (fmaxf(sqrtf(qs), 1e-12f) * fmaxf(sqrtf(ks), 1e-12f));
    float m = sim;
    #pragma unroll
    for (int d = 1; d < 16; d <<= 1) m = fmaxf(m, __shfl_xor(m, d, 16));
    float e = expf(sim - m);
    float ssum = e;
    #pragma unroll
    for (int d = 1; d < 16; d <<= 1) ssum += __shfl_xor(ssum, d, 16);
    attn[((size_t)(b*8 + h)*16 + i)*16 + j] = e / ssum;
}

// ---------- kernel 3: w_eff[b][o][c] = sum_i w_out[o][h*16+i]*attn[b][h][i][j] ----------
__global__ __launch_bounds__(256) void k_weff(const float* __restrict__ attn,
    const float* __restrict__ wout, bf16_t* __restrict__ weff)
{
    __shared__ float at[2048];
    int bid = blockIdx.x;           // 256 = 8b * 32
    int b = bid >> 5, ob = (bid & 31)*32;
    int t = threadIdx.x;
    #pragma unroll
    for (int r = 0; r < 8; r++) at[t + 256*r] = attn[(size_t)b*2048 + t + 256*r];
    __syncthreads();
    int c = t & 127, h = c >> 4, j = c & 15, oo = (t >> 7)*16;
    #pragma unroll
    for (int m = 0; m < 16; m++) {
        int o = ob + oo + m;
        float acc = 0.f;
        #pragma unroll
        for (int i2 = 0; i2 < 16; i2++)
            acc += wout[(size_t)o*INNER + h*16 + i2] * at[(h*16 + i2)*16 + j];
        weff[((size_t)b*DIM + o)*INNER + c] = (bf16_t)acc;
    }
}

// ---------- kernel 4: output GEMM  per b: (4096x128)x(128x1024), fp32 out ----------
__global__ __launch_bounds__(256) void k_out_gemm(const bf16_t* __restrict__ qkv,
    const bf16_t* __restrict__ weff, float* __restrict__ out)
{
    __shared__ bf16_t Al[128*136];
    __shared__ bf16_t Bl[128*136];
    int bid = blockIdx.x;           // 2048 = 8b * 32mt * 8nt
    int b = bid >> 8, rem = bid & 255;
    int mt = rem >> 3, nt = rem & 7;
    int tok0 = mt*128, o0 = nt*128;
    int t = threadIdx.x;
    #pragma unroll
    for (int rd = 0; rd < 8; rd++) {
        int r  = (t >> 4) + 16*rd;
        int c8 = (t & 15) * 8;
        *reinterpret_cast<uint4*>(&Al[r*136 + c8]) =
            *reinterpret_cast<const uint4*>(
                qkv + ((size_t)b*NTOK + tok0 + r)*QKVC + 256 + c8);   // v cols
        *reinterpret_cast<uint4*>(&Bl[r*136 + c8]) =
            *reinterpret_cast<const uint4*>(
                weff + ((size_t)b*DIM + o0 + r)*INNER + c8);
    }
    __syncthreads();
    int w = t >> 6, lane = t & 63, lr = lane & 15, lg = lane >> 4;
    int wr = (w & 1)*64, wc = (w >> 1)*64;
    f32x4 acc[4][4] = {};
    #pragma unroll
    for (int kk = 0; kk < 4; kk++) {
        int kb = kk*32 + lg*8;
        bf16x8 af[4], bfr[4];
        #pragma unroll
        for (int mi = 0; mi < 4; mi++)
            af[mi] = *reinterpret_cast<const bf16x8*>(&Al[(wr + mi*16 + lr)*136 + kb]);
        #pragma unroll
        for (int ni = 0; ni < 4; ni++)
            bfr[ni] = *reinterpret_cast<const bf16x8*>(&Bl[(wc + ni*16 + lr)*136 + kb]);
        #pragma unroll
        for (int mi = 0; mi < 4; mi++)
            #pragma unroll
            for (int ni = 0; ni < 4; ni++)
                acc[mi][ni] = __builtin_amdgcn_mfma_f32_16x16x32_bf16(
                    af[mi], bfr[ni], acc[mi][ni], 0, 0, 0);
    }
    #pragma unroll
    for (int mi = 0; mi < 4; mi++)
        #pragma unroll
        for (int ni = 0; ni < 4; ni++) {
            int col_g = o0 + wc + ni*16 + lr;
            #pragma unroll
            for (int r = 0; r < 4; r++) {
                int row_g = tok0 + wr + mi*16 + lg*4 + r;
                out[((size_t)b*NTOK + row_g)*DIM + col_g] = acc[mi][ni][r];
            }
        }
}

extern "C" void kernel_launch(void* const* d_in, const int* in_sizes, int n_in,
                              void* d_out, int out_size, void* d_ws, size_t ws_size,
                              hipStream_t stream)
{
    const float* x    = (const float*)d_in[0];   // 8*4096*1024
    const float* nw   = (const float*)d_in[1];   // 1024
    const float* wq   = (const float*)d_in[2];   // 384*1024
    const float* temp = (const float*)d_in[3];   // 8
    const float* wout = (const float*)d_in[4];   // 1024*128
    float* out = (float*)d_out;

    char* ws = (char*)d_ws;
    bf16_t* wqb   = (bf16_t*)(ws + OFF_WQ);
    bf16_t* qkv   = (bf16_t*)(ws + OFF_QKV);
    float*  stats = (float*)(ws + OFF_STATS);
    float*  attn  = (float*)(ws + OFF_ATTN);
    bf16_t* weff  = (bf16_t*)(ws + OFF_WEFF);

    k_wconv    <<<384,  256, 0, stream>>>(wq, nw, wqb);
    k_qkv_gemm <<<256,  512, 0, stream>>>(x, wqb, qkv, stats);
    k_attn     <<<64,   256, 0, stream>>>(stats, temp, attn);
    k_weff     <<<256,  256, 0, stream>>>(attn, wout, weff);
    k_out_gemm <<<2048, 256, 0, stream>>>(qkv, weff, out);
}

// Round 20
// 102.132 us; speedup vs baseline: 2.7957x; 2.7957x over previous
//
#include <hip/hip_runtime.h>
#include <hip/hip_bf16.h>
#include <stdint.h>

typedef __bf16 bf16_t;
typedef __bf16 bf16x8 __attribute__((ext_vector_type(8)));
typedef float  f32x4  __attribute__((ext_vector_type(4)));

#define DIM    1024
#define NTOK   4096
#define NB     8
#define ROWS   (NB*NTOK)   // 32768
#define QKVC   384
#define INNER  128

// global -> LDS direct copy, 16B per lane (dest = wave-uniform base + lane*16)
#define GLD16(g, l) __builtin_amdgcn_global_load_lds( \
    (const __attribute__((address_space(1))) void*)(g), \
    (__attribute__((address_space(3))) void*)(l), 16, 0, 0)

// workspace offsets (bytes)
#define OFF_WQ    131072u      // 384*1024 bf16   (768 KB)
#define OFF_QKV   1048576u     // 32768*384 bf16  (24 MB; only v cols written)
#define OFF_STATS 26214400u    // 256 chunks * 8 heads * 288 f32
#define OFF_ATTN  30932992u    // 8*8*16*16 f32
#define OFF_WEFF  30998528u    // 8*1024*128 bf16

// ---------- kernel 0: w_qkv * norm_weight -> bf16 ----------
__global__ __launch_bounds__(256) void k_wconv(const float* __restrict__ wq,
    const float* __restrict__ nw, bf16_t* __restrict__ wqb)
{
    int o = blockIdx.x;            // 384 rows
    int c = threadIdx.x * 4;
    float4 wv = *reinterpret_cast<const float4*>(wq + (size_t)o*DIM + c);
    float4 nv = *reinterpret_cast<const float4*>(nw + c);
    bf16_t* dst = wqb + (size_t)o*DIM + c;
    dst[0]=(bf16_t)(wv.x*nv.x); dst[1]=(bf16_t)(wv.y*nv.y);
    dst[2]=(bf16_t)(wv.z*nv.z); dst[3]=(bf16_t)(wv.w*nv.w);
}

// ---------- kernel 1: FUSED RMSNorm + QKV GEMM + Gram stats ----------
// EXACT R16 revert (measured best: 101.9 us total, qkv 77.7, no spill).
// R19 lesson (= R3 lesson): __launch_bounds__(512,4) forced <=128 regs/lane
// vs ~150 needed (96 acc + 16 staging + addr) -> 526 MB scratch, 250 us.
// (512,2) gives the 256-reg budget this accumulator footprint requires.
__global__ __launch_bounds__(512, 2) void k_qkv_gemm(const float* __restrict__ x,
    const bf16_t* __restrict__ wqb, bf16_t* __restrict__ qkv,
    float* __restrict__ stats)
{
    __shared__ bf16_t Al[2][128*64];   // 2 x 16 KB
    __shared__ bf16_t Bl[2][384*64];   // 2 x 48 KB (reused as 128x256 qk tile)
    __shared__ float srow[128];
    int mt = blockIdx.x;               // 256 blocks; chunk = 128 tokens
    int row0 = mt*128;
    int t = threadIdx.x;
    int lane = t & 63, lr = lane & 15, lg = lane >> 4;
    int w = t >> 6, wm = w >> 2, wn = w & 3;   // 2M x 4N wave grid

    // ---- A staging (regs): thread t owns row rA, fp32 elems fo..fo+15 of 64
    int rA = t >> 2;                   // 0..127
    int fo = (t & 3) * 16;
    const float* xrow = x + (size_t)(row0 + rA)*DIM + fo;
    int ws0 = ((t & 3)*2)     ^ (rA & 7);
    int ws1 = ((t & 3)*2 + 1) ^ (rA & 7);

    // ---- B staging (global_load_lds)
    int srB = t >> 3;                  // 0..63
    int sk8 = ((t & 7) ^ (srB & 7)) * 8;
    const bf16_t* bbase = wqb + (size_t)srB*DIM + sk8;
    int ldsoff = (t & ~63) * 8;        // wave-uniform dest base (elems)

    int rsw = lr & 7;                  // read-side slot XOR

    float4 u0, u1, u2, u3;             // 16 fp32 staging regs

#define LOADA(kt) do {                                                   \
        const float4* _xs = reinterpret_cast<const float4*>(xrow + (kt)*64); \
        u0 = _xs[0]; u1 = _xs[1]; u2 = _xs[2]; u3 = _xs[3];              \
    } while (0)

#define STAGEB(buf, kt) do {                                             \
        int _ko = (kt)*64;                                               \
        _Pragma("unroll")                                                \
        for (int _c = 0; _c < 6; _c++)                                   \
            GLD16(bbase + _ko + (size_t)(64*_c)*DIM,                     \
                  &Bl[buf][ldsoff + _c*4096]);                           \
    } while (0)

#define WRITEA(buf) do {                                                 \
        ssq += u0.x*u0.x + u0.y*u0.y + u0.z*u0.z + u0.w*u0.w             \
             + u1.x*u1.x + u1.y*u1.y + u1.z*u1.z + u1.w*u1.w             \
             + u2.x*u2.x + u2.y*u2.y + u2.z*u2.z + u2.w*u2.w             \
             + u3.x*u3.x + u3.y*u3.y + u3.z*u3.z + u3.w*u3.w;            \
        bf16x8 v0, v1;                                                   \
        v0[0]=(bf16_t)u0.x; v0[1]=(bf16_t)u0.y; v0[2]=(bf16_t)u0.z;      \
        v0[3]=(bf16_t)u0.w; v0[4]=(bf16_t)u1.x; v0[5]=(bf16_t)u1.y;      \
        v0[6]=(bf16_t)u1.z; v0[7]=(bf16_t)u1.w;                          \
        v1[0]=(bf16_t)u2.x; v1[1]=(bf16_t)u2.y; v1[2]=(bf16_t)u2.z;      \
        v1[3]=(bf16_t)u2.w; v1[4]=(bf16_t)u3.x; v1[5]=(bf16_t)u3.y;      \
        v1[6]=(bf16_t)u3.z; v1[7]=(bf16_t)u3.w;                          \
        *reinterpret_cast<bf16x8*>(&Al[buf][rA*64 + ws0*8]) = v0;        \
        *reinterpret_cast<bf16x8*>(&Al[buf][rA*64 + ws1*8]) = v1;        \
    } while (0)

    float ssq = 0.f;
    f32x4 acc[4][6] = {};

    // prologue: tile 0
    LOADA(0);
    STAGEB(0, 0);
    WRITEA(0);
    __syncthreads();

    for (int kt = 0; kt < 16; kt++) {
        int cur = kt & 1;
        if (kt < 15) {
            LOADA(kt + 1);
            STAGEB(cur ^ 1, kt + 1);
        }
        #pragma unroll
        for (int kk = 0; kk < 2; kk++) {
            int kb = ((kk*4 + lg) ^ rsw) * 8;
            bf16x8 af[4], bfr[6];
            #pragma unroll
            for (int mi = 0; mi < 4; mi++)
                af[mi] = *reinterpret_cast<const bf16x8*>(
                    &Al[cur][(wm*64 + mi*16 + lr)*64 + kb]);
            #pragma unroll
            for (int ni = 0; ni < 6; ni++)
                bfr[ni] = *reinterpret_cast<const bf16x8*>(
                    &Bl[cur][(wn*96 + ni*16 + lr)*64 + kb]);
            #pragma unroll
            for (int mi = 0; mi < 4; mi++)
                #pragma unroll
                for (int ni = 0; ni < 6; ni++)
                    acc[mi][ni] = __builtin_amdgcn_mfma_f32_16x16x32_bf16(
                        af[mi], bfr[ni], acc[mi][ni], 0, 0, 0);
        }
        if (kt < 15) WRITEA(cur ^ 1);
        __syncthreads();
    }
#undef LOADA
#undef STAGEB
#undef WRITEA

    // per-row sumsq: 4 consecutive threads share row rA
    ssq += __shfl_xor(ssq, 1, 64);
    ssq += __shfl_xor(ssq, 2, 64);
    if ((t & 3) == 0) srow[rA] = rsqrtf(ssq*(1.0f/DIM) + 1e-6f);
    __syncthreads();                    // also: all Bl reads done -> reusable

    // epilogue: v cols (>=256) -> global; q,k cols (<256) -> LDS qk tile
    bf16_t* qk = &Bl[0][0];             // 128 x 256 row-major (64 KB of 96)
    #pragma unroll
    for (int mi = 0; mi < 4; mi++)
        #pragma unroll
        for (int ni = 0; ni < 6; ni++) {
            int col_g = wn*96 + ni*16 + lr;
            #pragma unroll
            for (int rr = 0; rr < 4; rr++) {
                int rloc = wm*64 + mi*16 + lg*4 + rr;
                bf16_t val = (bf16_t)(acc[mi][ni][rr] * srow[rloc]);
                if (wn*96 + ni*16 >= 256)       // (wn,ni)-uniform branch
                    qkv[(size_t)(row0 + rloc)*QKVC + col_g] = val;
                else
                    qk[rloc*256 + col_g] = val;
            }
        }
    __syncthreads();

    // Gram phase: wave w = head h; gram[i][j] = sum_t q[t][h16+i]*k[t][h16+j]
    {
        int h = w;
        f32x4 g = {};
        #pragma unroll
        for (int ks = 0; ks < 4; ks++) {
            bf16x8 afr, bfr2;
            #pragma unroll
            for (int e = 0; e < 8; e++) {
                int tt = ks*32 + lg*8 + e;
                afr[e]  = qk[tt*256 + h*16 + lr];
                bfr2[e] = qk[tt*256 + 128 + h*16 + lr];
            }
            g = __builtin_amdgcn_mfma_f32_16x16x32_bf16(afr, bfr2, g, 0, 0, 0);
        }
        float* base = stats + ((size_t)mt*8 + h)*288;
        #pragma unroll
        for (int reg = 0; reg < 4; reg++)
            base[(lg*4 + reg)*16 + lr] = g[reg];   // row=lg*4+reg, col=lr
        float qs = 0.f, ks2 = 0.f;
        #pragma unroll
        for (int e = 0; e < 32; e++) {
            int tt = lg*32 + e;
            float qv = (float)qk[tt*256 + h*16 + lr];
            float kv = (float)qk[tt*256 + 128 + h*16 + lr];
            qs += qv*qv; ks2 += kv*kv;
        }
        qs  += __shfl_xor(qs, 16, 64);  qs  += __shfl_xor(qs, 32, 64);
        ks2 += __shfl_xor(ks2, 16, 64); ks2 += __shfl_xor(ks2, 32, 64);
        if (lane < 16) { base[256 + lr] = qs; base[272 + lr] = ks2; }
    }
}

// ---------- kernel 2: reduce partials, l2-normalize, temperature, softmax ----------
__global__ __launch_bounds__(256) void k_attn(const float* __restrict__ stats,
    const float* __restrict__ temp, float* __restrict__ attn)
{
    int bid = blockIdx.x;           // 64 = 8b * 8h
    int b = bid >> 3, h = bid & 7;
    int t = threadIdx.x, i = t >> 4, j = t & 15;
    float gsum = 0.f, qs = 0.f, ks = 0.f;
    for (int ch = 0; ch < 32; ch++) {        // 32 chunks of 128 tokens
        const float* base = stats + ((size_t)(b*32 + ch)*8 + h)*288;
        gsum += base[i*16 + j];
        qs   += base[256 + i];
        ks   += base[272 + j];
    }
    float et  = expf(temp[h]);
    float sim = gsum * et / (fmaxf(sqrtf(qs), 1e-12f) * fmaxf(sqrtf(ks), 1e-12f));
    float m = sim;
    #pragma unroll
    for (int d = 1; d < 16; d <<= 1) m = fmaxf(m, __shfl_xor(m, d, 16));
    float e = expf(sim - m);
    float ssum = e;
    #pragma unroll
    for (int d = 1; d < 16; d <<= 1) ssum += __shfl_xor(ssum, d, 16);
    attn[((size_t)(b*8 + h)*16 + i)*16 + j] = e / ssum;
}

// ---------- kernel 3: w_eff[b][o][c] = sum_i w_out[o][h*16+i]*attn[b][h][i][j] ----------
__global__ __launch_bounds__(256) void k_weff(const float* __restrict__ attn,
    const float* __restrict__ wout, bf16_t* __restrict__ weff)
{
    __shared__ float at[2048];
    int bid = blockIdx.x;           // 256 = 8b * 32
    int b = bid >> 5, ob = (bid & 31)*32;
    int t = threadIdx.x;
    #pragma unroll
    for (int r = 0; r < 8; r++) at[t + 256*r] = attn[(size_t)b*2048 + t + 256*r];
    __syncthreads();
    int c = t & 127, h = c >> 4, j = c & 15, oo = (t >> 7)*16;
    #pragma unroll
    for (int m = 0; m < 16; m++) {
        int o = ob + oo + m;
        float acc = 0.f;
        #pragma unroll
        for (int i2 = 0; i2 < 16; i2++)
            acc += wout[(size_t)o*INNER + h*16 + i2] * at[(h*16 + i2)*16 + j];
        weff[((size_t)b*DIM + o)*INNER + c] = (bf16_t)acc;
    }
}

// ---------- kernel 4: output GEMM  per b: (4096x128)x(128x1024), fp32 out ----------
__global__ __launch_bounds__(256) void k_out_gemm(const bf16_t* __restrict__ qkv,
    const bf16_t* __restrict__ weff, float* __restrict__ out)
{
    __shared__ bf16_t Al[128*136];
    __shared__ bf16_t Bl[128*136];
    int bid = blockIdx.x;           // 2048 = 8b * 32mt * 8nt
    int b = bid >> 8, rem = bid & 255;
    int mt = rem >> 3, nt = rem & 7;
    int tok0 = mt*128, o0 = nt*128;
    int t = threadIdx.x;
    #pragma unroll
    for (int rd = 0; rd < 8; rd++) {
        int r  = (t >> 4) + 16*rd;
        int c8 = (t & 15) * 8;
        *reinterpret_cast<uint4*>(&Al[r*136 + c8]) =
            *reinterpret_cast<const uint4*>(
                qkv + ((size_t)b*NTOK + tok0 + r)*QKVC + 256 + c8);   // v cols
        *reinterpret_cast<uint4*>(&Bl[r*136 + c8]) =
            *reinterpret_cast<const uint4*>(
                weff + ((size_t)b*DIM + o0 + r)*INNER + c8);
    }
    __syncthreads();
    int w = t >> 6, lane = t & 63, lr = lane & 15, lg = lane >> 4;
    int wr = (w & 1)*64, wc = (w >> 1)*64;
    f32x4 acc[4][4] = {};
    #pragma unroll
    for (int kk = 0; kk < 4; kk++) {
        int kb = kk*32 + lg*8;
        bf16x8 af[4], bfr[4];
        #pragma unroll
        for (int mi = 0; mi < 4; mi++)
            af[mi] = *reinterpret_cast<const bf16x8*>(&Al[(wr + mi*16 + lr)*136 + kb]);
        #pragma unroll
        for (int ni = 0; ni < 4; ni++)
            bfr[ni] = *reinterpret_cast<const bf16x8*>(&Bl[(wc + ni*16 + lr)*136 + kb]);
        #pragma unroll
        for (int mi = 0; mi < 4; mi++)
            #pragma unroll
            for (int ni = 0; ni < 4; ni++)
                acc[mi][ni] = __builtin_amdgcn_mfma_f32_16x16x32_bf16(
                    af[mi], bfr[ni], acc[mi][ni], 0, 0, 0);
    }
    #pragma unroll
    for (int mi = 0; mi < 4; mi++)
        #pragma unroll
        for (int ni = 0; ni < 4; ni++) {
            int col_g = o0 + wc + ni*16 + lr;
            #pragma unroll
            for (int r = 0; r < 4; r++) {
                int row_g = tok0 + wr + mi*16 + lg*4 + r;
                out[((size_t)b*NTOK + row_g)*DIM + col_g] = acc[mi][ni][r];
            }
        }
}

extern "C" void kernel_launch(void* const* d_in, const int* in_sizes, int n_in,
                              void* d_out, int out_size, void* d_ws, size_t ws_size,
                              hipStream_t stream)
{
    const float* x    = (const float*)d_in[0];   // 8*4096*1024
    const float* nw   = (const float*)d_in[1];   // 1024
    const float* wq   = (const float*)d_in[2];   // 384*1024
    const float* temp = (const float*)d_in[3];   // 8
    const float* wout = (const float*)d_in[4];   // 1024*128
    float* out = (float*)d_out;

    char* ws = (char*)d_ws;
    bf16_t* wqb   = (bf16_t*)(ws + OFF_WQ);
    bf16_t* qkv   = (bf16_t*)(ws + OFF_QKV);
    float*  stats = (float*)(ws + OFF_STATS);
    float*  attn  = (float*)(ws + OFF_ATTN);
    bf16_t* weff  = (bf16_t*)(ws + OFF_WEFF);

    k_wconv    <<<384,  256, 0, stream>>>(wq, nw, wqb);
    k_qkv_gemm <<<256,  512, 0, stream>>>(x, wqb, qkv, stats);
    k_attn     <<<64,   256, 0, stream>>>(stats, temp, attn);
    k_weff     <<<256,  256, 0, stream>>>(attn, wout, weff);
    k_out_gemm <<<2048, 256, 0, stream>>>(qkv, weff, out);
}